// Round 1
// baseline (45173.630 us; speedup 1.0000x reference)
//
#include <hip/hip_runtime.h>
#include <stdint.h>

#define TSTEPS 8192
#define HDIM 512
#define G4 2048   // 4*HDIM

// ---------------------------------------------------------------------------
// GEMM: C[M][2048] = A[M][512] @ W[2048][512]^T + b1[n] + b2[n]
// 64x64 tile, BK=32, 256 threads, K-major LDS so compute reads are b128.
// ---------------------------------------------------------------------------
__global__ __launch_bounds__(256) void gemm_nt_bias(
    const float* __restrict__ A, const float* __restrict__ W,
    const float* __restrict__ b1, const float* __restrict__ b2,
    float* __restrict__ C)
{
    __shared__ float sA[32][64];
    __shared__ float sW[32][64];
    const int tid = threadIdx.x;
    const int m0 = blockIdx.y * 64;
    const int n0 = blockIdx.x * 64;
    const int lr = tid >> 2;        // 0..63 tile row
    const int lk = (tid & 3) * 8;   // 0,8,16,24
    const int ty = tid >> 4;        // 0..15
    const int tx = tid & 15;

    float acc[4][4];
#pragma unroll
    for (int i = 0; i < 4; ++i)
#pragma unroll
        for (int j = 0; j < 4; ++j) acc[i][j] = 0.f;

    for (int k0 = 0; k0 < HDIM; k0 += 32) {
        float4 a0 = *(const float4*)&A[(size_t)(m0 + lr) * HDIM + k0 + lk];
        float4 a1 = *(const float4*)&A[(size_t)(m0 + lr) * HDIM + k0 + lk + 4];
        float4 w0 = *(const float4*)&W[(size_t)(n0 + lr) * HDIM + k0 + lk];
        float4 w1 = *(const float4*)&W[(size_t)(n0 + lr) * HDIM + k0 + lk + 4];
        __syncthreads();
        sA[lk + 0][lr] = a0.x; sA[lk + 1][lr] = a0.y; sA[lk + 2][lr] = a0.z; sA[lk + 3][lr] = a0.w;
        sA[lk + 4][lr] = a1.x; sA[lk + 5][lr] = a1.y; sA[lk + 6][lr] = a1.z; sA[lk + 7][lr] = a1.w;
        sW[lk + 0][lr] = w0.x; sW[lk + 1][lr] = w0.y; sW[lk + 2][lr] = w0.z; sW[lk + 3][lr] = w0.w;
        sW[lk + 4][lr] = w1.x; sW[lk + 5][lr] = w1.y; sW[lk + 6][lr] = w1.z; sW[lk + 7][lr] = w1.w;
        __syncthreads();
#pragma unroll 8
        for (int kk = 0; kk < 32; ++kk) {
            float4 av = *(const float4*)&sA[kk][ty * 4];
            float4 wv = *(const float4*)&sW[kk][tx * 4];
            acc[0][0] += av.x * wv.x; acc[0][1] += av.x * wv.y; acc[0][2] += av.x * wv.z; acc[0][3] += av.x * wv.w;
            acc[1][0] += av.y * wv.x; acc[1][1] += av.y * wv.y; acc[1][2] += av.y * wv.z; acc[1][3] += av.y * wv.w;
            acc[2][0] += av.z * wv.x; acc[2][1] += av.z * wv.y; acc[2][2] += av.z * wv.z; acc[2][3] += av.z * wv.w;
            acc[3][0] += av.w * wv.x; acc[3][1] += av.w * wv.y; acc[3][2] += av.w * wv.z; acc[3][3] += av.w * wv.w;
        }
    }
#pragma unroll
    for (int i = 0; i < 4; ++i) {
        const int m = m0 + ty * 4 + i;
#pragma unroll
        for (int j = 0; j < 4; ++j) {
            const int n = n0 + tx * 4 + j;
            C[(size_t)m * G4 + n] = acc[i][j] + b1[n] + b2[n];
        }
    }
}

// ---------------------------------------------------------------------------
// Persistent LSTM scan. 64 WGs x 256 threads. WG w owns hidden units
// j in [w*8, w*8+8). Wave v handles j_local = 2v + jj; lane = jj*32 + g*8 + kk.
// Each lane holds 64 W_hh weights (row g*512+j, k-chunk kk) in VGPRs.
// h broadcast via packed {tag,value} 8B agent-scope atomics, depth-2 ring.
// Consuming tag for step t is (t+1); neither 0x00000000 nor 0xAAAAAAAA poison
// can match a live tag.
// ---------------------------------------------------------------------------
__device__ __forceinline__ float fast_sigmoid(float x) {
    return 1.f / (1.f + __expf(-x));
}
__device__ __forceinline__ float fast_tanh(float x) {
    return 1.f - 2.f / (__expf(2.f * x) + 1.f);
}

__global__ __launch_bounds__(256) void lstm_scan(
    const float* __restrict__ Whh,   // [2048][512]
    const float* __restrict__ xg,    // [T][2048]
    const float* __restrict__ h0,    // [512]
    const float* __restrict__ c0,    // [512]
    float* __restrict__ hseq,        // [T][512]
    unsigned long long* __restrict__ ring)  // [2][512]
{
    const int w    = blockIdx.x;       // 0..63
    const int tid  = threadIdx.x;      // 0..255
    const int wave = tid >> 6;         // 0..3
    const int lane = tid & 63;
    const int jj   = lane >> 5;        // 0..1
    const int g    = (lane >> 3) & 3;  // gate: 0=i 1=f 2=g 3=o
    const int kk   = lane & 7;         // k-chunk (64 elems each)
    const int j    = w * 8 + wave * 2 + jj;
    const int row  = g * HDIM + j;

    // register-resident weights: 64 f32
    float wreg[64];
    {
        const float* wp = Whh + (size_t)row * HDIM + kk * 64;
#pragma unroll
        for (int u = 0; u < 16; ++u) {
            float4 v = *(const float4*)&wp[u * 4];
            wreg[u * 4 + 0] = v.x; wreg[u * 4 + 1] = v.y;
            wreg[u * 4 + 2] = v.z; wreg[u * 4 + 3] = v.w;
        }
    }

    float c = c0[j];   // redundant across the 32 lanes of this jj-group

    // publish initial h with tag 1 into ring slot 0 (one lane per j)
    if (g == 0 && kk == 0) {
        union { float f; unsigned u; } hu; hu.f = h0[j];
        __hip_atomic_store(&ring[j],
                           (((unsigned long long)1u) << 32) | hu.u,
                           __ATOMIC_RELAXED, __HIP_MEMORY_SCOPE_AGENT);
    }

    __shared__ float hbuf[HDIM];

    for (int t = 0; t < TSTEPS; ++t) {
        // prefetch this step's xg value (independent of the recurrence)
        const float xv = xg[(size_t)t * G4 + row];

        // poll the two ring entries this thread stages
        const unsigned tagw = (unsigned)(t + 1);
        unsigned long long* slot = ring + (size_t)(t & 1) * HDIM;
        unsigned long long p0, p1;
        for (;;) {
            p0 = __hip_atomic_load(&slot[2 * tid],     __ATOMIC_RELAXED, __HIP_MEMORY_SCOPE_AGENT);
            p1 = __hip_atomic_load(&slot[2 * tid + 1], __ATOMIC_RELAXED, __HIP_MEMORY_SCOPE_AGENT);
            if ((unsigned)(p0 >> 32) == tagw && (unsigned)(p1 >> 32) == tagw) break;
        }
        union { unsigned u; float f; } a0, a1;
        a0.u = (unsigned)p0; a1.u = (unsigned)p1;
        hbuf[2 * tid]     = a0.f;
        hbuf[2 * tid + 1] = a1.f;
        __syncthreads();

        // 64-element partial dot
        float s0 = 0.f, s1 = 0.f, s2 = 0.f, s3 = 0.f;
        const float* hp = &hbuf[kk * 64];
#pragma unroll
        for (int u = 0; u < 16; ++u) {
            s0 += wreg[4 * u + 0] * hp[4 * u + 0];
            s1 += wreg[4 * u + 1] * hp[4 * u + 1];
            s2 += wreg[4 * u + 2] * hp[4 * u + 2];
            s3 += wreg[4 * u + 3] * hp[4 * u + 3];
        }
        float s = (s0 + s1) + (s2 + s3);
        __syncthreads();   // hbuf fully consumed; next iter may overwrite

        // reduce across the 8 kk lanes (bits 0..2)
        s += __shfl_xor(s, 1);
        s += __shfl_xor(s, 2);
        s += __shfl_xor(s, 4);
        s += xv;

        // per-row activation
        const float act = (g == 2) ? fast_tanh(s) : fast_sigmoid(s);

        // gather the 4 gates of this lane's j (any kk lane holds the full sum)
        const int base = jj * 32 + kk;
        const float iv = __shfl(act, base + 0);
        const float fv = __shfl(act, base + 8);
        const float gv = __shfl(act, base + 16);
        const float ov = __shfl(act, base + 24);

        c = fv * c + iv * gv;
        const float h = ov * fast_tanh(c);

        if (lane == jj * 32) {    // g==0 && kk==0: one publisher per j
            hseq[(size_t)t * HDIM + j] = h;
            union { float f; unsigned u; } hu; hu.f = h;
            __hip_atomic_store(&ring[(size_t)((t + 1) & 1) * HDIM + j],
                               (((unsigned long long)(unsigned)(t + 2)) << 32) | hu.u,
                               __ATOMIC_RELAXED, __HIP_MEMORY_SCOPE_AGENT);
        }
    }
}

// ---------------------------------------------------------------------------
// Head + BCE loss. One wave per timestep (1024 waves, 8 steps each).
// loss = -mean(y*max(log p,-100) + (1-y)*max(log1p(-p),-100)) over T x 2.
// ---------------------------------------------------------------------------
__global__ __launch_bounds__(256) void head_loss(
    const float* __restrict__ h2,   // [T][512]
    const float* __restrict__ Wh,   // [2][512]
    const float* __restrict__ bh,   // [2]
    const float* __restrict__ y,    // [T][2]
    float* __restrict__ out)
{
    const int tid  = threadIdx.x;
    const int lane = tid & 63;
    const int wv   = tid >> 6;
    const int gw   = blockIdx.x * 4 + wv;   // 0..1023

    float w0[8], w1[8];
#pragma unroll
    for (int u = 0; u < 8; ++u) {
        w0[u] = Wh[lane * 8 + u];
        w1[u] = Wh[HDIM + lane * 8 + u];
    }

    float lsum = 0.f;
    for (int t = gw; t < TSTEPS; t += 1024) {
        const float* hp = h2 + (size_t)t * HDIM + lane * 8;
        float4 hv0 = *(const float4*)&hp[0];
        float4 hv1 = *(const float4*)&hp[4];
        float a0 = hv0.x * w0[0] + hv0.y * w0[1] + hv0.z * w0[2] + hv0.w * w0[3]
                 + hv1.x * w0[4] + hv1.y * w0[5] + hv1.z * w0[6] + hv1.w * w0[7];
        float a1 = hv0.x * w1[0] + hv0.y * w1[1] + hv0.z * w1[2] + hv0.w * w1[3]
                 + hv1.x * w1[4] + hv1.y * w1[5] + hv1.z * w1[6] + hv1.w * w1[7];
#pragma unroll
        for (int m = 1; m < 64; m <<= 1) {
            a0 += __shfl_xor(a0, m);
            a1 += __shfl_xor(a1, m);
        }
        if (lane == 0) {
            const float z0 = a0 + bh[0];
            const float z1 = a1 + bh[1];
            const float p0 = 1.f / (1.f + __expf(-z0));
            const float p1 = 1.f / (1.f + __expf(-z1));
            const float lp0  = fmaxf(__logf(p0), -100.f);
            const float lp1  = fmaxf(__logf(p1), -100.f);
            const float l1p0 = fmaxf(log1pf(-p0), -100.f);
            const float l1p1 = fmaxf(log1pf(-p1), -100.f);
            const float y0 = y[(size_t)t * 2 + 0];
            const float y1 = y[(size_t)t * 2 + 1];
            lsum += y0 * lp0 + (1.f - y0) * l1p0;
            lsum += y1 * lp1 + (1.f - y1) * l1p1;
        }
    }

    __shared__ float red[4];
    if (lane == 0) red[wv] = lsum;
    __syncthreads();
    if (tid == 0) {
        const float s = red[0] + red[1] + red[2] + red[3];
        atomicAdd(out, s * (-1.f / (float)(TSTEPS * 2)));
    }
}

// ---------------------------------------------------------------------------
extern "C" void kernel_launch(void* const* d_in, const int* in_sizes, int n_in,
                              void* d_out, int out_size, void* d_ws, size_t ws_size,
                              hipStream_t stream)
{
    const float* x     = (const float*)d_in[0];   // [8192][1][512]
    const float* truth = (const float*)d_in[1];   // [8192][1][2]
    const float* h0    = (const float*)d_in[2];   // [2][1][512]
    const float* c0    = (const float*)d_in[3];   // [2][1][512]
    const float* Wih0  = (const float*)d_in[4];
    const float* Whh0  = (const float*)d_in[5];
    const float* bih0  = (const float*)d_in[6];
    const float* bhh0  = (const float*)d_in[7];
    const float* Wih1  = (const float*)d_in[8];
    const float* Whh1  = (const float*)d_in[9];
    const float* bih1  = (const float*)d_in[10];
    const float* bhh1  = (const float*)d_in[11];
    const float* Whead = (const float*)d_in[12];
    const float* bhead = (const float*)d_in[13];

    char* ws = (char*)d_ws;
    float* xg    = (float*)ws;                                  // 64 MB [T][2048]
    float* h1seq = (float*)(ws + (((size_t)64) << 20));         // 16 MB [T][512]
    float* h2seq = (float*)(ws + (((size_t)80) << 20));         // 16 MB [T][512]
    unsigned long long* ring0 = (unsigned long long*)(ws + (((size_t)96) << 20)); // 8 KB
    unsigned long long* ring1 = ring0 + 2 * HDIM;                                  // 8 KB

    hipMemsetAsync(d_out, 0, (size_t)out_size * sizeof(float), stream);

    dim3 gemm_grid(G4 / 64, TSTEPS / 64);  // (32, 128)
    gemm_nt_bias<<<gemm_grid, 256, 0, stream>>>(x, Wih0, bih0, bhh0, xg);
    lstm_scan<<<64, 256, 0, stream>>>(Whh0, xg, h0, c0, h1seq, ring0);
    gemm_nt_bias<<<gemm_grid, 256, 0, stream>>>(h1seq, Wih1, bih1, bhh1, xg);
    lstm_scan<<<64, 256, 0, stream>>>(Whh1, xg, h0 + HDIM, c0 + HDIM, h2seq, ring1);
    head_loss<<<256, 256, 0, stream>>>(h2seq, Whead, bhead, truth, (float*)d_out);
}

// Round 2
// 18179.037 us; speedup vs baseline: 2.4849x; 2.4849x over previous
//
#include <hip/hip_runtime.h>
#include <stdint.h>

#define TSTEPS 8192
#define HDIM 512
#define G4 2048   // 4*HDIM
#define R0D 64    // ring0 depth (h1 ring, consumed by both layers)

typedef unsigned long long ull;

// ---------------------------------------------------------------------------
// GEMM: C[M][2048] = A[M][512] @ W[2048][512]^T + b1[n] + b2[n]
// Used once: xg1 = x @ W_ih0^T + (b_ih0 + b_hh0).
// ---------------------------------------------------------------------------
__global__ __launch_bounds__(256) void gemm_nt_bias(
    const float* __restrict__ A, const float* __restrict__ W,
    const float* __restrict__ b1, const float* __restrict__ b2,
    float* __restrict__ C)
{
    __shared__ float sA[32][64];
    __shared__ float sW[32][64];
    const int tid = threadIdx.x;
    const int m0 = blockIdx.y * 64;
    const int n0 = blockIdx.x * 64;
    const int lr = tid >> 2;        // 0..63 tile row
    const int lk = (tid & 3) * 8;   // 0,8,16,24
    const int ty = tid >> 4;        // 0..15
    const int tx = tid & 15;

    float acc[4][4];
#pragma unroll
    for (int i = 0; i < 4; ++i)
#pragma unroll
        for (int jq = 0; jq < 4; ++jq) acc[i][jq] = 0.f;

    for (int k0 = 0; k0 < HDIM; k0 += 32) {
        float4 a0 = *(const float4*)&A[(size_t)(m0 + lr) * HDIM + k0 + lk];
        float4 a1 = *(const float4*)&A[(size_t)(m0 + lr) * HDIM + k0 + lk + 4];
        float4 w0 = *(const float4*)&W[(size_t)(n0 + lr) * HDIM + k0 + lk];
        float4 w1 = *(const float4*)&W[(size_t)(n0 + lr) * HDIM + k0 + lk + 4];
        __syncthreads();
        sA[lk + 0][lr] = a0.x; sA[lk + 1][lr] = a0.y; sA[lk + 2][lr] = a0.z; sA[lk + 3][lr] = a0.w;
        sA[lk + 4][lr] = a1.x; sA[lk + 5][lr] = a1.y; sA[lk + 6][lr] = a1.z; sA[lk + 7][lr] = a1.w;
        sW[lk + 0][lr] = w0.x; sW[lk + 1][lr] = w0.y; sW[lk + 2][lr] = w0.z; sW[lk + 3][lr] = w0.w;
        sW[lk + 4][lr] = w1.x; sW[lk + 5][lr] = w1.y; sW[lk + 6][lr] = w1.z; sW[lk + 7][lr] = w1.w;
        __syncthreads();
#pragma unroll 8
        for (int kki = 0; kki < 32; ++kki) {
            float4 av = *(const float4*)&sA[kki][ty * 4];
            float4 wv = *(const float4*)&sW[kki][tx * 4];
            acc[0][0] += av.x * wv.x; acc[0][1] += av.x * wv.y; acc[0][2] += av.x * wv.z; acc[0][3] += av.x * wv.w;
            acc[1][0] += av.y * wv.x; acc[1][1] += av.y * wv.y; acc[1][2] += av.y * wv.z; acc[1][3] += av.y * wv.w;
            acc[2][0] += av.z * wv.x; acc[2][1] += av.z * wv.y; acc[2][2] += av.z * wv.z; acc[2][3] += av.z * wv.w;
            acc[3][0] += av.w * wv.x; acc[3][1] += av.w * wv.y; acc[3][2] += av.w * wv.z; acc[3][3] += av.w * wv.w;
        }
    }
#pragma unroll
    for (int i = 0; i < 4; ++i) {
        const int m = m0 + ty * 4 + i;
#pragma unroll
        for (int jq = 0; jq < 4; ++jq) {
            const int n = n0 + tx * 4 + jq;
            C[(size_t)m * G4 + n] = acc[i][jq] + b1[n] + b2[n];
        }
    }
}

// ---------------------------------------------------------------------------
__device__ __forceinline__ ull pack_th(unsigned tag, float v) {
    union { float f; unsigned u; } x; x.f = v;
    return ((ull)tag << 32) | (ull)x.u;
}
__device__ __forceinline__ float unpack_v(ull p) {
    union { unsigned u; float f; } x; x.u = (unsigned)p;
    return x.f;
}

// ---------------------------------------------------------------------------
// Fused 2-layer persistent LSTM scan. 128 WGs x 256 threads.
//   blocks 0..63  : layer 1 — recurrent matvec W_hh0 @ h1(t-1) + xg[t] (GEMM'd)
//   blocks 64..127: layer 2 — W_ih1 @ h1(t) + W_hh1 @ h2(t-1) + bias, on the fly
// WG w owns hidden units j in [w*8, w*8+8). Lane = jj*32 + g*8 + kk; each lane
// holds the 64-element k-chunk (chunk kk) of row (g*512+j) in VGPRs, quad-
// rotated by kk so LDS b128 reads are bank-conflict-free.
//
// h1 ring: depth 64, tag = seq+1 (seq s holds h1 after step s-1; s=0 initial).
//   L1 step t consumes tag t+1, publishes tag t+2 (slot (t+1)&63), guarded by
//   prog >= t-56 (prog = L2-WG0's publish tag; L2 WGs are within 1 step of
//   each other, and needed bound is prog >= t-61 — margin 5).
// h2 ring: depth 2 (self-recurrence only; depth-2 is provably safe).
// Tags <= 8194, so neither 0x00000000 nor 0xAAAAAAAA poison can match.
// ---------------------------------------------------------------------------
__global__ __launch_bounds__(256, 1) void lstm_fused(
    const float* __restrict__ Whh0,   // [2048][512]
    const float* __restrict__ xg,     // [T][2048]  (= x@Wih0^T + b0)
    const float* __restrict__ Wih1,   // [2048][512]
    const float* __restrict__ Whh1,   // [2048][512]
    const float* __restrict__ bih1,   // [2048]
    const float* __restrict__ bhh1,   // [2048]
    const float* __restrict__ h0,     // [2][512]
    const float* __restrict__ c0,     // [2][512]
    float* __restrict__ h2seq,        // [T][512]
    ull* __restrict__ ring0,          // [64][512]
    ull* __restrict__ ring1,          // [2][512]
    unsigned* __restrict__ prog)      // [1], memset 0 before launch
{
    const int L2   = (blockIdx.x >= 64) ? 1 : 0;
    const int w    = L2 ? (int)blockIdx.x - 64 : (int)blockIdx.x;
    const int tid  = threadIdx.x;
    const int wave = tid >> 6;
    const int lane = tid & 63;
    const int jj   = lane >> 5;
    const int g    = (lane >> 3) & 3;
    const int kk   = lane & 7;
    const int j    = w * 8 + wave * 2 + jj;
    const int row  = g * HDIM + j;

    // register-resident weights, quad-rotated by kk (bank-conflict-free reads)
    float4 wqA[16], wqB[16];
    {
        const float* WA = L2 ? Wih1 : Whh0;
        const float4* wpA = (const float4*)(WA + (size_t)row * HDIM + kk * 64);
#pragma unroll
        for (int u = 0; u < 16; ++u) wqA[u] = wpA[(u + kk) & 15];
    }
    if (L2) {
        const float4* wpB = (const float4*)(Whh1 + (size_t)row * HDIM + kk * 64);
#pragma unroll
        for (int u = 0; u < 16; ++u) wqB[u] = wpB[(u + kk) & 15];
    }
    const float bias = L2 ? (bih1[row] + bhh1[row]) : 0.f;
    float c = c0[(L2 ? HDIM : 0) + j];

    const bool pub = (lane == jj * 32);   // g==0 && kk==0: one publisher per j
    if (pub) {
        const float h = h0[(L2 ? HDIM : 0) + j];
        ull* r = L2 ? ring1 : ring0;
        __hip_atomic_store(&r[j], pack_th(1u, h),
                           __ATOMIC_RELAXED, __HIP_MEMORY_SCOPE_AGENT);
    }

    __shared__ float hA[HDIM];
    __shared__ float hB[HDIM];   // layer-2 only

    for (int t = 0; t < TSTEPS; ++t) {
        float xv = 0.f;
        unsigned pg = 0;
        if (!L2) {
            xv = xg[(size_t)t * G4 + row];           // prefetch, off critical path
            if (pub && t >= R0D - 1)                  // prefetch back-pressure guard
                pg = __hip_atomic_load(prog, __ATOMIC_RELAXED, __HIP_MEMORY_SCOPE_AGENT);
        }

        // ---- poll + stage h into LDS --------------------------------------
        if (!L2) {
            ull* s = ring0 + (size_t)(t & (R0D - 1)) * HDIM;
            const unsigned tg = (unsigned)(t + 1);
            ull p0 = __hip_atomic_load(&s[2 * tid],     __ATOMIC_RELAXED, __HIP_MEMORY_SCOPE_AGENT);
            ull p1 = __hip_atomic_load(&s[2 * tid + 1], __ATOMIC_RELAXED, __HIP_MEMORY_SCOPE_AGENT);
            while ((unsigned)(p0 >> 32) != tg || (unsigned)(p1 >> 32) != tg) {
                __builtin_amdgcn_s_sleep(1);
                p0 = __hip_atomic_load(&s[2 * tid],     __ATOMIC_RELAXED, __HIP_MEMORY_SCOPE_AGENT);
                p1 = __hip_atomic_load(&s[2 * tid + 1], __ATOMIC_RELAXED, __HIP_MEMORY_SCOPE_AGENT);
            }
            hA[2 * tid]     = unpack_v(p0);
            hA[2 * tid + 1] = unpack_v(p1);
        } else {
            ull* sa = ring0 + (size_t)((t + 1) & (R0D - 1)) * HDIM;   // h1(t)
            ull* sb = ring1 + (size_t)(t & 1) * HDIM;                  // h2(t-1)
            const unsigned ta = (unsigned)(t + 2);
            const unsigned tb = (unsigned)(t + 1);
            ull p0 = __hip_atomic_load(&sa[2 * tid],     __ATOMIC_RELAXED, __HIP_MEMORY_SCOPE_AGENT);
            ull p1 = __hip_atomic_load(&sa[2 * tid + 1], __ATOMIC_RELAXED, __HIP_MEMORY_SCOPE_AGENT);
            ull q0 = __hip_atomic_load(&sb[2 * tid],     __ATOMIC_RELAXED, __HIP_MEMORY_SCOPE_AGENT);
            ull q1 = __hip_atomic_load(&sb[2 * tid + 1], __ATOMIC_RELAXED, __HIP_MEMORY_SCOPE_AGENT);
            while ((unsigned)(p0 >> 32) != ta || (unsigned)(p1 >> 32) != ta ||
                   (unsigned)(q0 >> 32) != tb || (unsigned)(q1 >> 32) != tb) {
                __builtin_amdgcn_s_sleep(1);
                p0 = __hip_atomic_load(&sa[2 * tid],     __ATOMIC_RELAXED, __HIP_MEMORY_SCOPE_AGENT);
                p1 = __hip_atomic_load(&sa[2 * tid + 1], __ATOMIC_RELAXED, __HIP_MEMORY_SCOPE_AGENT);
                q0 = __hip_atomic_load(&sb[2 * tid],     __ATOMIC_RELAXED, __HIP_MEMORY_SCOPE_AGENT);
                q1 = __hip_atomic_load(&sb[2 * tid + 1], __ATOMIC_RELAXED, __HIP_MEMORY_SCOPE_AGENT);
            }
            hA[2 * tid]     = unpack_v(p0);
            hA[2 * tid + 1] = unpack_v(p1);
            hB[2 * tid]     = unpack_v(q0);
            hB[2 * tid + 1] = unpack_v(q1);
        }
        __syncthreads();

        // ---- 64-element (L1) or 128-element (L2) partial dot --------------
        float s0 = 0.f, s1 = 0.f, s2 = 0.f, s3 = 0.f;
        {
            const float4* ha4 = (const float4*)&hA[kk * 64];
#pragma unroll
            for (int u = 0; u < 16; ++u) {
                const float4 hv = ha4[(u + kk) & 15];
                s0 += wqA[u].x * hv.x; s1 += wqA[u].y * hv.y;
                s2 += wqA[u].z * hv.z; s3 += wqA[u].w * hv.w;
            }
        }
        if (L2) {
            const float4* hb4 = (const float4*)&hB[kk * 64];
#pragma unroll
            for (int u = 0; u < 16; ++u) {
                const float4 hv = hb4[(u + kk) & 15];
                s0 += wqB[u].x * hv.x; s1 += wqB[u].y * hv.y;
                s2 += wqB[u].z * hv.z; s3 += wqB[u].w * hv.w;
            }
        }
        float s = (s0 + s1) + (s2 + s3);
        __syncthreads();   // hA/hB fully consumed; next iter may overwrite

        // reduce across the 8 kk lanes
        s += __shfl_xor(s, 1);
        s += __shfl_xor(s, 2);
        s += __shfl_xor(s, 4);
        s += L2 ? bias : xv;

        // branchless activation: gates σ(s); cell-gate tanh(s)=2σ(2s)-1
        const float sc  = (g == 2) ? 2.f : 1.f;
        const float sig = 1.f / (1.f + __expf(-sc * s));
        const float act = sc * sig - (sc - 1.f);

        const int base = jj * 32 + kk;
        const float iv = __shfl(act, base);
        const float fv = __shfl(act, base + 8);
        const float gv = __shfl(act, base + 16);
        const float ov = __shfl(act, base + 24);

        c = fv * c + iv * gv;
        const float h = ov * (1.f - 2.f / (__expf(2.f * c) + 1.f));

        if (!L2) {
            if (pub) {
                if (t >= R0D - 1) {
                    while (pg + 56 < (unsigned)t) {     // need pg >= t-61; margin 5
                        __builtin_amdgcn_s_sleep(4);
                        pg = __hip_atomic_load(prog, __ATOMIC_RELAXED, __HIP_MEMORY_SCOPE_AGENT);
                    }
                }
                __hip_atomic_store(&ring0[(size_t)((t + 1) & (R0D - 1)) * HDIM + j],
                                   pack_th((unsigned)(t + 2), h),
                                   __ATOMIC_RELAXED, __HIP_MEMORY_SCOPE_AGENT);
            }
        } else {
            if (pub) {
                __hip_atomic_store(&ring1[(size_t)((t + 1) & 1) * HDIM + j],
                                   pack_th((unsigned)(t + 2), h),
                                   __ATOMIC_RELAXED, __HIP_MEMORY_SCOPE_AGENT);
                if (w == 0 && tid == 0)
                    __hip_atomic_store(prog, (unsigned)(t + 2),
                                       __ATOMIC_RELAXED, __HIP_MEMORY_SCOPE_AGENT);
            }
            if (lane == jj * 32 + 1)          // separate lane: h2seq store off
                h2seq[(size_t)t * HDIM + j] = h;   // the publish critical path
        }
    }
}

// ---------------------------------------------------------------------------
// Head + BCE loss.
// ---------------------------------------------------------------------------
__global__ __launch_bounds__(256) void head_loss(
    const float* __restrict__ h2,   // [T][512]
    const float* __restrict__ Wh,   // [2][512]
    const float* __restrict__ bh,   // [2]
    const float* __restrict__ y,    // [T][2]
    float* __restrict__ out)
{
    const int tid  = threadIdx.x;
    const int lane = tid & 63;
    const int wv   = tid >> 6;
    const int gw   = blockIdx.x * 4 + wv;   // 0..1023

    float w0[8], w1[8];
#pragma unroll
    for (int u = 0; u < 8; ++u) {
        w0[u] = Wh[lane * 8 + u];
        w1[u] = Wh[HDIM + lane * 8 + u];
    }

    float lsum = 0.f;
    for (int t = gw; t < TSTEPS; t += 1024) {
        const float* hp = h2 + (size_t)t * HDIM + lane * 8;
        float4 hv0 = *(const float4*)&hp[0];
        float4 hv1 = *(const float4*)&hp[4];
        float a0 = hv0.x * w0[0] + hv0.y * w0[1] + hv0.z * w0[2] + hv0.w * w0[3]
                 + hv1.x * w0[4] + hv1.y * w0[5] + hv1.z * w0[6] + hv1.w * w0[7];
        float a1 = hv0.x * w1[0] + hv0.y * w1[1] + hv0.z * w1[2] + hv0.w * w1[3]
                 + hv1.x * w1[4] + hv1.y * w1[5] + hv1.z * w1[6] + hv1.w * w1[7];
#pragma unroll
        for (int m = 1; m < 64; m <<= 1) {
            a0 += __shfl_xor(a0, m);
            a1 += __shfl_xor(a1, m);
        }
        if (lane == 0) {
            const float z0 = a0 + bh[0];
            const float z1 = a1 + bh[1];
            const float p0 = 1.f / (1.f + __expf(-z0));
            const float p1 = 1.f / (1.f + __expf(-z1));
            const float lp0  = fmaxf(__logf(p0), -100.f);
            const float lp1  = fmaxf(__logf(p1), -100.f);
            const float l1p0 = fmaxf(log1pf(-p0), -100.f);
            const float l1p1 = fmaxf(log1pf(-p1), -100.f);
            const float y0 = y[(size_t)t * 2 + 0];
            const float y1 = y[(size_t)t * 2 + 1];
            lsum += y0 * lp0 + (1.f - y0) * l1p0;
            lsum += y1 * lp1 + (1.f - y1) * l1p1;
        }
    }

    __shared__ float red[4];
    if (lane == 0) red[wv] = lsum;
    __syncthreads();
    if (tid == 0) {
        const float ssum = red[0] + red[1] + red[2] + red[3];
        atomicAdd(out, ssum * (-1.f / (float)(TSTEPS * 2)));
    }
}

// ---------------------------------------------------------------------------
extern "C" void kernel_launch(void* const* d_in, const int* in_sizes, int n_in,
                              void* d_out, int out_size, void* d_ws, size_t ws_size,
                              hipStream_t stream)
{
    const float* x     = (const float*)d_in[0];   // [8192][1][512]
    const float* truth = (const float*)d_in[1];   // [8192][1][2]
    const float* h0    = (const float*)d_in[2];   // [2][1][512]
    const float* c0    = (const float*)d_in[3];   // [2][1][512]
    const float* Wih0  = (const float*)d_in[4];
    const float* Whh0  = (const float*)d_in[5];
    const float* bih0  = (const float*)d_in[6];
    const float* bhh0  = (const float*)d_in[7];
    const float* Wih1  = (const float*)d_in[8];
    const float* Whh1  = (const float*)d_in[9];
    const float* bih1  = (const float*)d_in[10];
    const float* bhh1  = (const float*)d_in[11];
    const float* Whead = (const float*)d_in[12];
    const float* bhead = (const float*)d_in[13];

    char* ws = (char*)d_ws;
    float*    xg    = (float*)ws;                               // 64 MB [T][2048]
    ull*      ring0 = (ull*)(ws + (((size_t)64) << 20));        // 256 KB [64][512]
    ull*      ring1 = (ull*)(ws + (((size_t)64) << 20) + (512 << 10));  // 8 KB [2][512]
    unsigned* prog  = (unsigned*)(ws + (((size_t)65) << 20));   // 4 B
    float*    h2seq = (float*)(ws + (((size_t)66) << 20));      // 16 MB [T][512]

    hipMemsetAsync(d_out, 0, (size_t)out_size * sizeof(float), stream);
    hipMemsetAsync(prog, 0, sizeof(unsigned), stream);

    dim3 gemm_grid(G4 / 64, TSTEPS / 64);  // (32, 128)
    gemm_nt_bias<<<gemm_grid, 256, 0, stream>>>(x, Wih0, bih0, bhh0, xg);
    lstm_fused<<<128, 256, 0, stream>>>(Whh0, xg, Wih1, Whh1, bih1, bhh1,
                                        h0, c0, h2seq, ring0, ring1, prog);
    head_loss<<<256, 256, 0, stream>>>(h2seq, Whead, bhead, truth, (float*)d_out);
}

// Round 3
// 14797.520 us; speedup vs baseline: 3.0528x; 1.2285x over previous
//
#include <hip/hip_runtime.h>
#include <stdint.h>

#define TSTEPS 8192
#define HDIM 512
#define G4 2048   // 4*HDIM

typedef unsigned long long ull;

// ---------------------------------------------------------------------------
__device__ __forceinline__ ull pack_th(unsigned tag, float v) {
    union { float f; unsigned u; } x; x.f = v;
    return ((ull)tag << 32) | (ull)x.u;
}
__device__ __forceinline__ float unpack_v(ull p) {
    union { unsigned u; float f; } x; x.u = (unsigned)p;
    return x.f;
}

// ---------------------------------------------------------------------------
// Fused 2-layer persistent LSTM scan. 128 WGs x 256 threads.
//   blocks 0..63  : layer 1.  recurrent = W_hh0 @ h1(t-1)   feed = W_ih0 @ x(t)
//   blocks 64..127: layer 2.  recurrent = W_hh1 @ h2(t-1)   feed = W_ih1 @ h1(t)
// Both paths are code-identical (same register footprint -> no spill):
//   wqA = recurrent weights, wqB = feed weights, 64 f32 each per lane,
//   quad-rotated by kk so LDS float4 reads are bank-conflict-free.
// WG w owns hidden units j in [w*8, w*8+8). Lane = jj*32 + g*8 + kk.
//
// ring0 = FULL-HISTORY h1 ring: slot s holds h1 seq s (s=0 initial state),
//   tag = s+1. Written once, never overwritten -> L1 never waits for L2,
//   no back-pressure. 8193 slots * 512 * 8B = 33.6 MB in d_ws.
// ring1 = depth-2 h2 self-ring (provably safe: publishing step t+1 requires
//   all WGs consumed step t, which implies slot being overwritten is dead).
// Tags <= 8194; poison 0xAAAAAAAA / 0x00000000 can never match.
//
// Per-step phases:
//   A: feed dot from hB (staged last iter) -> pre   [off critical path]
//   B: poll recurrent self-ring -> hA, sync
//   C: s = dotA + pre, reduce over 8 kk-lanes, +bias, activations, c/h update
//   D: publish h (one lane per j)
//   E: stage feed(t+1) into hB (L1: x-load issued in A; L2: poll h1(t+1),
//      already published since L1 runs ahead), sync
// ---------------------------------------------------------------------------
__global__ __launch_bounds__(256, 1) void lstm_fused(
    const float* __restrict__ x,      // [T][512]
    const float* __restrict__ Whh0,   // [2048][512]
    const float* __restrict__ Wih0,   // [2048][512]
    const float* __restrict__ bih0,   // [2048]
    const float* __restrict__ bhh0,   // [2048]
    const float* __restrict__ Wih1,   // [2048][512]
    const float* __restrict__ Whh1,   // [2048][512]
    const float* __restrict__ bih1,   // [2048]
    const float* __restrict__ bhh1,   // [2048]
    const float* __restrict__ h0,     // [2][512]
    const float* __restrict__ c0,     // [2][512]
    float* __restrict__ h2seq,        // [T][512]
    ull* __restrict__ ring0,          // [T+1][512]
    ull* __restrict__ ring1)          // [2][512]
{
    const int L2   = (blockIdx.x >= 64) ? 1 : 0;
    const int w    = L2 ? (int)blockIdx.x - 64 : (int)blockIdx.x;
    const int tid  = threadIdx.x;
    const int wave = tid >> 6;
    const int lane = tid & 63;
    const int jj   = lane >> 5;
    const int g    = (lane >> 3) & 3;
    const int kk   = lane & 7;
    const int j    = w * 8 + wave * 2 + jj;
    const int row  = g * HDIM + j;

    // register-resident weights, quad-rotated by kk
    float4 wqA[16], wqB[16];   // recurrent / feed
    {
        const float* WA = L2 ? Whh1 : Whh0;
        const float* WB = L2 ? Wih1 : Wih0;
        const float4* wpA = (const float4*)(WA + (size_t)row * HDIM + kk * 64);
        const float4* wpB = (const float4*)(WB + (size_t)row * HDIM + kk * 64);
#pragma unroll
        for (int u = 0; u < 16; ++u) wqA[u] = wpA[(u + kk) & 15];
#pragma unroll
        for (int u = 0; u < 16; ++u) wqB[u] = wpB[(u + kk) & 15];
    }
    const float bias = L2 ? (bih1[row] + bhh1[row]) : (bih0[row] + bhh0[row]);
    float c = c0[(L2 ? HDIM : 0) + j];

    const bool pub = (lane == jj * 32);   // g==0 && kk==0: one publisher per j
    if (pub) {
        const float h = h0[(L2 ? HDIM : 0) + j];
        ull* r = L2 ? ring1 : ring0;      // slot 0, tag 1
        __hip_atomic_store(&r[j], pack_th(1u, h),
                           __ATOMIC_RELAXED, __HIP_MEMORY_SCOPE_AGENT);
    }

    __shared__ float hA[HDIM];   // recurrent vector
    __shared__ float hB[HDIM];   // feed vector

    // ---- pre-loop: stage feed(0) into hB ----------------------------------
    if (!L2) {
        float2 v = *(const float2*)&x[2 * tid];             // x(0)
        hB[2 * tid] = v.x; hB[2 * tid + 1] = v.y;
    } else {
        ull* s = ring0 + (size_t)1 * HDIM;                  // h1 seq 1, tag 2
        ull p0 = __hip_atomic_load(&s[2 * tid],     __ATOMIC_RELAXED, __HIP_MEMORY_SCOPE_AGENT);
        ull p1 = __hip_atomic_load(&s[2 * tid + 1], __ATOMIC_RELAXED, __HIP_MEMORY_SCOPE_AGENT);
        while ((unsigned)(p0 >> 32) != 2u || (unsigned)(p1 >> 32) != 2u) {
            __builtin_amdgcn_s_sleep(1);
            p0 = __hip_atomic_load(&s[2 * tid],     __ATOMIC_RELAXED, __HIP_MEMORY_SCOPE_AGENT);
            p1 = __hip_atomic_load(&s[2 * tid + 1], __ATOMIC_RELAXED, __HIP_MEMORY_SCOPE_AGENT);
        }
        hB[2 * tid]     = unpack_v(p0);
        hB[2 * tid + 1] = unpack_v(p1);
    }
    __syncthreads();

    for (int t = 0; t < TSTEPS; ++t) {
        // ---- A: feed dot + issue next x load ------------------------------
        float2 xnext;
        if (!L2) {
            const int rn = (t + 1 < TSTEPS) ? t + 1 : 0;
            xnext = *(const float2*)&x[(size_t)rn * HDIM + 2 * tid];
        }
        float p0f = 0.f, p1f = 0.f, p2f = 0.f, p3f = 0.f;
        {
            const float4* hb4 = (const float4*)&hB[kk * 64];
#pragma unroll
            for (int u = 0; u < 16; ++u) {
                const float4 hv = hb4[(u + kk) & 15];
                p0f += wqB[u].x * hv.x; p1f += wqB[u].y * hv.y;
                p2f += wqB[u].z * hv.z; p3f += wqB[u].w * hv.w;
            }
        }
        const float pre = (p0f + p1f) + (p2f + p3f);

        // ---- B: poll recurrent self-ring -> hA ----------------------------
        {
            ull* s = L2 ? (ring1 + (size_t)(t & 1) * HDIM)
                        : (ring0 + (size_t)t * HDIM);
            const unsigned tg = (unsigned)(t + 1);
            ull q0 = __hip_atomic_load(&s[2 * tid],     __ATOMIC_RELAXED, __HIP_MEMORY_SCOPE_AGENT);
            ull q1 = __hip_atomic_load(&s[2 * tid + 1], __ATOMIC_RELAXED, __HIP_MEMORY_SCOPE_AGENT);
            while ((unsigned)(q0 >> 32) != tg || (unsigned)(q1 >> 32) != tg) {
                __builtin_amdgcn_s_sleep(1);
                q0 = __hip_atomic_load(&s[2 * tid],     __ATOMIC_RELAXED, __HIP_MEMORY_SCOPE_AGENT);
                q1 = __hip_atomic_load(&s[2 * tid + 1], __ATOMIC_RELAXED, __HIP_MEMORY_SCOPE_AGENT);
            }
            hA[2 * tid]     = unpack_v(q0);
            hA[2 * tid + 1] = unpack_v(q1);
        }
        __syncthreads();

        // ---- C: recurrent dot + nonlinearity ------------------------------
        float s0 = 0.f, s1 = 0.f, s2 = 0.f, s3 = 0.f;
        {
            const float4* ha4 = (const float4*)&hA[kk * 64];
#pragma unroll
            for (int u = 0; u < 16; ++u) {
                const float4 hv = ha4[(u + kk) & 15];
                s0 += wqA[u].x * hv.x; s1 += wqA[u].y * hv.y;
                s2 += wqA[u].z * hv.z; s3 += wqA[u].w * hv.w;
            }
        }
        float s = (s0 + s1) + (s2 + s3) + pre;

        s += __shfl_xor(s, 1);
        s += __shfl_xor(s, 2);
        s += __shfl_xor(s, 4);
        s += bias;

        // branchless: gates sigma(s); cell-gate tanh(s)=2*sigma(2s)-1
        const float sc  = (g == 2) ? 2.f : 1.f;
        const float sig = 1.f / (1.f + __expf(-sc * s));
        const float act = sc * sig - (sc - 1.f);

        const int base = jj * 32 + kk;
        const float iv = __shfl(act, base);
        const float fv = __shfl(act, base + 8);
        const float gv = __shfl(act, base + 16);
        const float ov = __shfl(act, base + 24);

        c = fv * c + iv * gv;
        const float h = ov * (1.f - 2.f / (__expf(2.f * c) + 1.f));

        // ---- D: publish ---------------------------------------------------
        if (pub) {
            if (!L2) {
                __hip_atomic_store(&ring0[(size_t)(t + 1) * HDIM + j],
                                   pack_th((unsigned)(t + 2), h),
                                   __ATOMIC_RELAXED, __HIP_MEMORY_SCOPE_AGENT);
            } else {
                __hip_atomic_store(&ring1[(size_t)((t + 1) & 1) * HDIM + j],
                                   pack_th((unsigned)(t + 2), h),
                                   __ATOMIC_RELAXED, __HIP_MEMORY_SCOPE_AGENT);
            }
        }
        if (L2 && lane == jj * 32 + 1)     // off the publish critical path
            h2seq[(size_t)t * HDIM + j] = h;

        // ---- E: stage feed(t+1) into hB -----------------------------------
        if (t + 1 < TSTEPS) {
            if (!L2) {
                hB[2 * tid] = xnext.x; hB[2 * tid + 1] = xnext.y;
            } else {
                ull* s2p = ring0 + (size_t)(t + 2) * HDIM;   // h1 seq t+2
                const unsigned tg2 = (unsigned)(t + 3);
                ull q0 = __hip_atomic_load(&s2p[2 * tid],     __ATOMIC_RELAXED, __HIP_MEMORY_SCOPE_AGENT);
                ull q1 = __hip_atomic_load(&s2p[2 * tid + 1], __ATOMIC_RELAXED, __HIP_MEMORY_SCOPE_AGENT);
                while ((unsigned)(q0 >> 32) != tg2 || (unsigned)(q1 >> 32) != tg2) {
                    __builtin_amdgcn_s_sleep(1);
                    q0 = __hip_atomic_load(&s2p[2 * tid],     __ATOMIC_RELAXED, __HIP_MEMORY_SCOPE_AGENT);
                    q1 = __hip_atomic_load(&s2p[2 * tid + 1], __ATOMIC_RELAXED, __HIP_MEMORY_SCOPE_AGENT);
                }
                hB[2 * tid]     = unpack_v(q0);
                hB[2 * tid + 1] = unpack_v(q1);
            }
            __syncthreads();
        }
    }
}

// ---------------------------------------------------------------------------
// Head + BCE loss.
// ---------------------------------------------------------------------------
__global__ __launch_bounds__(256) void head_loss(
    const float* __restrict__ h2,   // [T][512]
    const float* __restrict__ Wh,   // [2][512]
    const float* __restrict__ bh,   // [2]
    const float* __restrict__ y,    // [T][2]
    float* __restrict__ out)
{
    const int tid  = threadIdx.x;
    const int lane = tid & 63;
    const int wv   = tid >> 6;
    const int gw   = blockIdx.x * 4 + wv;   // 0..1023

    float w0[8], w1[8];
#pragma unroll
    for (int u = 0; u < 8; ++u) {
        w0[u] = Wh[lane * 8 + u];
        w1[u] = Wh[HDIM + lane * 8 + u];
    }

    float lsum = 0.f;
    for (int t = gw; t < TSTEPS; t += 1024) {
        const float* hp = h2 + (size_t)t * HDIM + lane * 8;
        float4 hv0 = *(const float4*)&hp[0];
        float4 hv1 = *(const float4*)&hp[4];
        float a0 = hv0.x * w0[0] + hv0.y * w0[1] + hv0.z * w0[2] + hv0.w * w0[3]
                 + hv1.x * w0[4] + hv1.y * w0[5] + hv1.z * w0[6] + hv1.w * w0[7];
        float a1 = hv0.x * w1[0] + hv0.y * w1[1] + hv0.z * w1[2] + hv0.w * w1[3]
                 + hv1.x * w1[4] + hv1.y * w1[5] + hv1.z * w1[6] + hv1.w * w1[7];
#pragma unroll
        for (int m = 1; m < 64; m <<= 1) {
            a0 += __shfl_xor(a0, m);
            a1 += __shfl_xor(a1, m);
        }
        if (lane == 0) {
            const float z0 = a0 + bh[0];
            const float z1 = a1 + bh[1];
            const float p0 = 1.f / (1.f + __expf(-z0));
            const float p1 = 1.f / (1.f + __expf(-z1));
            const float lp0  = fmaxf(__logf(p0), -100.f);
            const float lp1  = fmaxf(__logf(p1), -100.f);
            const float l1p0 = fmaxf(log1pf(-p0), -100.f);
            const float l1p1 = fmaxf(log1pf(-p1), -100.f);
            const float y0 = y[(size_t)t * 2 + 0];
            const float y1 = y[(size_t)t * 2 + 1];
            lsum += y0 * lp0 + (1.f - y0) * l1p0;
            lsum += y1 * lp1 + (1.f - y1) * l1p1;
        }
    }

    __shared__ float red[4];
    if (lane == 0) red[wv] = lsum;
    __syncthreads();
    if (tid == 0) {
        const float ssum = red[0] + red[1] + red[2] + red[3];
        atomicAdd(out, ssum * (-1.f / (float)(TSTEPS * 2)));
    }
}

// ---------------------------------------------------------------------------
extern "C" void kernel_launch(void* const* d_in, const int* in_sizes, int n_in,
                              void* d_out, int out_size, void* d_ws, size_t ws_size,
                              hipStream_t stream)
{
    const float* x     = (const float*)d_in[0];   // [8192][1][512]
    const float* truth = (const float*)d_in[1];   // [8192][1][2]
    const float* h0    = (const float*)d_in[2];   // [2][1][512]
    const float* c0    = (const float*)d_in[3];   // [2][1][512]
    const float* Wih0  = (const float*)d_in[4];
    const float* Whh0  = (const float*)d_in[5];
    const float* bih0  = (const float*)d_in[6];
    const float* bhh0  = (const float*)d_in[7];
    const float* Wih1  = (const float*)d_in[8];
    const float* Whh1  = (const float*)d_in[9];
    const float* bih1  = (const float*)d_in[10];
    const float* bhh1  = (const float*)d_in[11];
    const float* Whead = (const float*)d_in[12];
    const float* bhead = (const float*)d_in[13];

    char* ws = (char*)d_ws;
    ull*   ring0 = (ull*)ws;                               // 33.6 MB [8193][512]
    ull*   ring1 = (ull*)(ws + (((size_t)34) << 20));      // 8 KB   [2][512]
    float* h2seq = (float*)(ws + (((size_t)35) << 20));    // 16 MB  [T][512]

    hipMemsetAsync(d_out, 0, (size_t)out_size * sizeof(float), stream);

    lstm_fused<<<128, 256, 0, stream>>>(x, Whh0, Wih0, bih0, bhh0,
                                        Wih1, Whh1, bih1, bhh1,
                                        h0, c0, h2seq, ring0, ring1);
    head_loss<<<256, 256, 0, stream>>>(h2seq, Whead, bhead, truth, (float*)d_out);
}